// Round 1
// 87.174 us; speedup vs baseline: 1.0770x; 1.0770x over previous
//
#include <hip/hip_runtime.h>
#include <math.h>

#define NQ   4
#define NH   8
#define NL   2
#define DIM  16   // 2^NQ
#define EMB  32
#define TPB  64   // tokens per block

#define LO_SCALE 4096.0f          // 2^12: lo-part pre-scale (keeps f16 normal)
#define LO_INV   (1.0f/4096.0f)

typedef _Float16 f16x8  __attribute__((ext_vector_type(8)));
typedef float    f32x16 __attribute__((ext_vector_type(16)));

// ---------------------------------------------------------------------------
// Setup: build per-head circuit unitary U (16x16 complex) in registers
// (one thread per (head h, basis column col)), then emit it as MFMA
// A-fragments for v_mfma_f32_32x32x16_f16 with M = [Ur; Ui] (32x16):
//   A[row][k]: lane = (row&31) + 32*(k>>3), elem e = k&7
// Two buffers: hi = f16(U), lo = f16((U - hi) * 2^12)  (3-pass split).
// Layout in ws (halfs): Ahi[8 heads][64 lanes][8], Alo at +4096.
// ---------------------------------------------------------------------------
__global__ void build_unitaries_kernel(const float* __restrict__ params,
                                       float* __restrict__ Uws) {
    int tid = threadIdx.x;          // 0..127
    int h   = tid >> 4;
    int col = tid & 15;

    float re[DIM], im[DIM];
#pragma unroll
    for (int j = 0; j < DIM; ++j) { re[j] = (j == col) ? 1.f : 0.f; im[j] = 0.f; }

#pragma unroll
    for (int l = 0; l < NL; ++l) {
#pragma unroll
        for (int q = 0; q < NQ; ++q) {
            const float* p = params + ((h * NL + l) * NQ + q) * 3;
            const int m = 1 << (3 - q);      // compile-time after unroll
            // RX
            {
                float s, c; __sincosf(0.5f * p[0], &s, &c);
#pragma unroll
                for (int j = 0; j < DIM; ++j) {
                    if (j & m) continue;
                    const int j1 = j | m;
                    float r0 = re[j], i0 = im[j], r1 = re[j1], i1 = im[j1];
                    re[j]  = c * r0 + s * i1;
                    im[j]  = c * i0 - s * r1;
                    re[j1] = s * i0 + c * r1;
                    im[j1] = -s * r0 + c * i1;
                }
            }
            // RY
            {
                float s, c; __sincosf(0.5f * p[1], &s, &c);
#pragma unroll
                for (int j = 0; j < DIM; ++j) {
                    if (j & m) continue;
                    const int j1 = j | m;
                    float r0 = re[j], i0 = im[j], r1 = re[j1], i1 = im[j1];
                    re[j]  = c * r0 - s * r1;
                    im[j]  = c * i0 - s * i1;
                    re[j1] = s * r0 + c * r1;
                    im[j1] = s * i0 + c * i1;
                }
            }
            // RZ
            {
                float s, c; __sincosf(0.5f * p[2], &s, &c);
#pragma unroll
                for (int j = 0; j < DIM; ++j) {
                    if (j & m) continue;
                    const int j1 = j | m;
                    float r0 = re[j], i0 = im[j], r1 = re[j1], i1 = im[j1];
                    re[j]  = c * r0 + s * i0;
                    im[j]  = c * i0 - s * r0;
                    re[j1] = c * r1 - s * i1;
                    im[j1] = c * i1 + s * r1;
                }
            }
        }
        // CNOT ring: (0,1),(1,2),(2,3),(3,0)
#pragma unroll
        for (int e = 0; e < NQ; ++e) {
            const int cm = 1 << (3 - e), tm = 1 << (3 - ((e + 1) & 3));
#pragma unroll
            for (int j = 0; j < DIM; ++j) {
                if ((j & cm) && !(j & tm)) {
                    const int j1 = j | tm;
                    float tr = re[j]; re[j] = re[j1]; re[j1] = tr;
                    float ti = im[j]; im[j] = im[j1]; im[j1] = ti;
                }
            }
        }
    }

    // ---- emit A-fragments (this thread owns column k=col, all 32 M-rows) ----
    _Float16* Ah = (_Float16*)Uws;        // 4096 halfs
    _Float16* Al = Ah + 4096;             // 4096 halfs
    const int khigh = col >> 3, e = col & 7;
#pragma unroll
    for (int j = 0; j < DIM; ++j) {
        {   // real part -> M-row j
            const float v = re[j];
            const _Float16 h16 = (_Float16)v;
            const float lo = (v - (float)h16) * LO_SCALE;
            const int lane = j + 32 * khigh;
            Ah[(h * 64 + lane) * 8 + e] = h16;
            Al[(h * 64 + lane) * 8 + e] = (_Float16)lo;
        }
        {   // imag part -> M-row 16+j
            const float v = im[j];
            const _Float16 h16 = (_Float16)v;
            const float lo = (v - (float)h16) * LO_SCALE;
            const int lane = 16 + j + 32 * khigh;
            Ah[(h * 64 + lane) * 8 + e] = h16;
            Al[(h * 64 + lane) * 8 + e] = (_Float16)lo;
        }
    }
}

// ---------------------------------------------------------------------------
// Main: block = 512 threads = 8 waves; wave w = head w, 64 tokens per block
// in two 32-token MFMA groups.
// Phase 1 (MFMA): amp = [Ur;Ui] @ a  via 3x v_mfma_f32_32x32x16_f16
//   (hi*hi into accH; lo*hi + hi*lo, lo pre-scaled 2^12, into accL).
//   C layout: col=lane&31 (token), row=(reg&3)+8*(reg>>2)+4*(lane>>5);
//   reg r and r+8 are real/imag of the same basis state j -> pj lane-local;
//   Z-expvals = signed sums over 8 regs + one shfl_xor(32) cross-half add.
// Phase 2: unchanged GEMV out = b + W @ ev from LDS (verified earlier).
// ---------------------------------------------------------------------------
__global__ __launch_bounds__(512, 4)
void qmha_kernel(const float* __restrict__ x,
                 const float* __restrict__ Uws,
                 const float* __restrict__ W,
                 const float* __restrict__ bvec,
                 float* __restrict__ out,
                 int ntok) {
    __shared__ float evs[EMB * TPB];   // evs[k][t], k = h*4+q, stride 64
    __shared__ float Wt[EMB * 36];     // Wt[k][e],  stride 36

    const int tid  = threadIdx.x;
    const int tok0 = blockIdx.x * TPB;

    // ---- stage W transposed into LDS: Wt[k][e] = W[e][k] ----
    {
        const int idx = tid * 2;               // 0..1022
        const float2 w2 = *(const float2*)(W + idx);
        const int e0 = idx >> 5, k0 = idx & 31;
        const int e1 = (idx + 1) >> 5, k1 = (idx + 1) & 31;
        Wt[k0 * 36 + e0] = w2.x;
        Wt[k1 * 36 + e1] = w2.y;
    }

    // ---- phase 1: quantum circuit via MFMA ----
    {
        const int h    = tid >> 6;       // wave id = head (wave-uniform)
        const int lane = tid & 63;
        const int lh   = lane & 31;      // token slot within 32-group
        const int hi   = lane >> 5;      // K-half (k = hi*8 + e)

        // per-lane A-fragments for this head: 2 x dwordx4, L2-hot, loaded once
        const _Float16* Ah = (const _Float16*)Uws;
        const _Float16* Al = Ah + 4096;
        const f16x8 Afh = *(const f16x8*)(Ah + (h * 64 + lane) * 8);
        const f16x8 Afl = *(const f16x8*)(Al + (h * 64 + lane) * 8);

#pragma unroll
        for (int g = 0; g < 2; ++g) {
            const int t    = g * 32 + lh;
            const int tok  = tok0 + t;
            const int tokc = (tok < ntok) ? tok : (ntok - 1);

            const float4 xa = *(const float4*)(x + (size_t)tokc * EMB + h * NQ);
            float c0, s0, c1, s1, c2, s2, c3, s3;
            __sincosf(0.5f * xa.x, &s0, &c0);
            __sincosf(0.5f * xa.y, &s1, &c1);
            __sincosf(0.5f * xa.z, &s2, &c2);
            __sincosf(0.5f * xa.w, &s3, &c3);

            // psi0[k] = p01[k>>2] * p23[k&3]; this lane needs k = hi*8+e,
            // so only p01[2*hi], p01[2*hi+1] are required.
            const float f  = hi ? s0 : c0;
            const float pA = f * c1, pB = f * s1;
            const float p23[4] = {c2 * c3, c2 * s3, s2 * c3, s2 * s3};

            f16x8 bh, bl;
#pragma unroll
            for (int e = 0; e < 8; ++e) {
                const float av = ((e >> 2) ? pB : pA) * p23[e & 3];
                const _Float16 ah16 = (_Float16)av;
                bh[e] = ah16;
                bl[e] = (_Float16)((av - (float)ah16) * LO_SCALE);
            }

            f32x16 accH, accL;
#pragma unroll
            for (int i = 0; i < 16; ++i) { accH[i] = 0.f; accL[i] = 0.f; }
            accH = __builtin_amdgcn_mfma_f32_32x32x16_f16(Afh, bh, accH, 0, 0, 0);
            accL = __builtin_amdgcn_mfma_f32_32x32x16_f16(Afl, bh, accL, 0, 0, 0);
            accL = __builtin_amdgcn_mfma_f32_32x32x16_f16(Afh, bl, accL, 0, 0, 0);

            // pj for j = (r&3) + 8*(r>>2) + 4*hi, r = 0..7
            float pj[8];
#pragma unroll
            for (int r = 0; r < 8; ++r) {
                const float ar = fmaf(accL[r],     LO_INV, accH[r]);
                const float ai = fmaf(accL[r + 8], LO_INV, accH[r + 8]);
                pj[r] = ar * ar + ai * ai;
            }
            // sign bits: j&8 = 8*(r>>2), j&4 = 4*hi, j&2 = r&2, j&1 = r&1
            const float s01 = pj[0] + pj[1], s23 = pj[2] + pj[3];
            const float s45 = pj[4] + pj[5], s67 = pj[6] + pj[7];
            const float sa = s01 + s23, sb = s45 + s67;
            float ev0 = sa - sb;
            const float tot = sa + sb;
            float ev1 = hi ? -tot : tot;
            float ev2 = (s01 + s45) - (s23 + s67);
            float ev3 = (pj[0] - pj[1]) + (pj[2] - pj[3]) +
                        (pj[4] - pj[5]) + (pj[6] - pj[7]);
            ev0 += __shfl_xor(ev0, 32);
            ev1 += __shfl_xor(ev1, 32);
            ev2 += __shfl_xor(ev2, 32);
            ev3 += __shfl_xor(ev3, 32);

            if (hi == 0 && tok < ntok) {
                evs[(h * 4 + 0) * TPB + t] = ev0;
                evs[(h * 4 + 1) * TPB + t] = ev1;
                evs[(h * 4 + 2) * TPB + t] = ev2;
                evs[(h * 4 + 3) * TPB + t] = ev3;
            }
        }
    }
    __syncthreads();

    // ---- phase 2: out[tok][e] = b[e] + sum_k ev[tok][k] * W[e][k] ----
    {
        const int t2 = tid >> 3;       // 0..63
        const int eg = tid & 7;        // 0..7 -> outputs eg*4..+3
        const int tok = tok0 + t2;
        if (tok < ntok) {
            const float4 bv = *(const float4*)(bvec + eg * 4);
            float o0 = bv.x, o1 = bv.y, o2 = bv.z, o3 = bv.w;
#pragma unroll
            for (int k = 0; k < EMB; ++k) {
                const float evk = evs[k * TPB + t2];
                const float4 wk = *(const float4*)(Wt + k * 36 + eg * 4);
                o0 = fmaf(wk.x, evk, o0);
                o1 = fmaf(wk.y, evk, o1);
                o2 = fmaf(wk.z, evk, o2);
                o3 = fmaf(wk.w, evk, o3);
            }
            float4 v; v.x = o0; v.y = o1; v.z = o2; v.w = o3;
            *(float4*)(out + (size_t)tok * EMB + eg * 4) = v;
        }
    }
}

extern "C" void kernel_launch(void* const* d_in, const int* in_sizes, int n_in,
                              void* d_out, int out_size, void* d_ws, size_t ws_size,
                              hipStream_t stream) {
    const float* x      = (const float*)d_in[0];
    const float* params = (const float*)d_in[1];
    const float* W_out  = (const float*)d_in[2];
    const float* b_out  = (const float*)d_in[3];
    float*       out    = (float*)d_out;
    float*       Uws    = (float*)d_ws;   // 8192 halfs = 16 KB (A-frags hi|lo)

    const int ntok = in_sizes[0] / EMB;   // B*S = 131072

    hipLaunchKernelGGL(build_unitaries_kernel, dim3(1), dim3(128), 0, stream,
                       params, Uws);

    const int blocks = (ntok + TPB - 1) / TPB;
    hipLaunchKernelGGL(qmha_kernel, dim3(blocks), dim3(512), 0, stream,
                       x, Uws, W_out, b_out, out, ntok);
}